// Round 1
// baseline (662.170 us; speedup 1.0000x reference)
//
#include <hip/hip_runtime.h>
#include <math.h>

// FFM forward: out[b] = sigmoid( bias + sum_f Wl[g(b,f)]
//                                + sum_{i<j} dot(W[j, g(b,i)], W[i, g(b,j)]) )
// g(b,f) = x[b,f] + f*V_FIELD.  Memory-bound random-gather problem:
// 380 x 256B vector gathers per sample (~797 MB total for B=8192).

#define FF 20
#define V_FIELD 5000
#define TOTAL (FF * V_FIELD)   // 100000
#define DD 64
#define SPB 4                  // samples per 256-thread block (1 wave each)

__global__ __launch_bounds__(256) void ffm_kernel(
    const int* __restrict__ x,
    const float* __restrict__ W,
    const float* __restrict__ Wl,
    const float* __restrict__ bias,
    float* __restrict__ out)
{
    __shared__ int g[SPB][FF];
    const int t = threadIdx.x;
    const int sbase = blockIdx.x * SPB;

    // Stage global vocab indices for this block's 4 samples.
    if (t < SPB * FF) {
        const int s = t / FF, f = t % FF;
        g[s][f] = x[(sbase + s) * FF + f] + f * V_FIELD;
    }
    __syncthreads();

    const int wave = t >> 6;
    const int lane = t & 63;
    const int b = sbase + wave;

    // Hoist this wave's 20 indices into SGPRs: all lanes read the same LDS
    // word, readfirstlane makes the load bases scalar (saddr + lane*4).
    int gi[FF];
#pragma unroll
    for (int i = 0; i < FF; ++i)
        gi[i] = __builtin_amdgcn_readfirstlane(g[wave][i]);

    // 190 pairs, lane = dim. Two coalesced 256B wave-loads per pair.
    // 4 accumulators to break the FMA dependency chain.
    float acc0 = 0.f, acc1 = 0.f, acc2 = 0.f, acc3 = 0.f;
    int p = 0;
#pragma unroll
    for (int i = 0; i < FF - 1; ++i) {
#pragma unroll
        for (int j = i + 1; j < FF; ++j) {
            const float a = W[((size_t)j * TOTAL + gi[i]) * DD + lane];
            const float c = W[((size_t)i * TOTAL + gi[j]) * DD + lane];
            switch (p & 3) {
                case 0: acc0 = fmaf(a, c, acc0); break;
                case 1: acc1 = fmaf(a, c, acc1); break;
                case 2: acc2 = fmaf(a, c, acc2); break;
                default: acc3 = fmaf(a, c, acc3); break;
            }
            ++p;
        }
    }
    float acc = (acc0 + acc1) + (acc2 + acc3);

    // Linear term: lanes 0..19 each add one Wl entry (per-lane LDS index).
    if (lane < FF) acc += Wl[g[wave][lane]];

    // Wave-64 reduction.
#pragma unroll
    for (int off = 32; off > 0; off >>= 1)
        acc += __shfl_down(acc, off, 64);

    if (lane == 0)
        out[b] = 1.f / (1.f + expf(-(acc + bias[0])));
}

extern "C" void kernel_launch(void* const* d_in, const int* in_sizes, int n_in,
                              void* d_out, int out_size, void* d_ws, size_t ws_size,
                              hipStream_t stream) {
    const int*   x    = (const int*)d_in[0];
    const float* W    = (const float*)d_in[1];
    const float* Wl   = (const float*)d_in[2];
    const float* bias = (const float*)d_in[3];
    float* out = (float*)d_out;

    const int nB = out_size;            // 8192 samples
    dim3 grid(nB / SPB), block(256);
    hipLaunchKernelGGL(ffm_kernel, grid, block, 0, stream,
                       x, W, Wl, bias, out);
}

// Round 2
// 661.394 us; speedup vs baseline: 1.0012x; 1.0012x over previous
//
#include <hip/hip_runtime.h>
#include <math.h>

// FFM forward: out[b] = sigmoid( bias + sum_f Wl[g(b,f)]
//                                + sum_{i<j} dot(W[j, g(b,i)], W[i, g(b,j)]) )
// g(b,f) = x[b,f] + f*V_FIELD.
//
// R2: latency-bound fix. 4 rows per global_load_dwordx4 (64 lanes =
// 4 pairs x 16 lanes x float4 = 1KB/instr), rolled loop over an LDS
// offset table, low VGPR for high occupancy. Final sum is over ALL
// pairs+dims, so lane->pair assignment needs no shuffle alignment.

#define FF 20
#define V_FIELD 5000
#define TOTAL (FF * V_FIELD)   // 100000
#define DD 64
#define SPB 4                  // samples per 256-thread block (1 wave each)
#define NP 190                 // F*(F-1)/2 pairs
#define NPP 192                // padded to multiple of 4

__global__ __launch_bounds__(256, 4) void ffm_kernel(
    const int* __restrict__ x,
    const float* __restrict__ W,
    const float* __restrict__ Wl,
    const float* __restrict__ bias,
    float* __restrict__ out)
{
    __shared__ int g[SPB][FF];
    __shared__ short pi[NPP], pj[NPP];
    __shared__ unsigned offA[SPB][NPP], offB[SPB][NPP];

    const int t = threadIdx.x;
    const int sbase = blockIdx.x * SPB;

    // Stage vocab indices (global row within a field's 5000-slot range).
    if (t < SPB * FF) {
        const int s = t / FF, f = t % FF;
        g[s][f] = x[(sbase + s) * FF + f] + f * V_FIELD;
    }
    // Pair tables (i<j), same for all samples. Pads -> dummy (0,1).
    if (t < NPP) {
        int pp = (t >= NP) ? 0 : t;
        int i = 0;
        while (pp >= FF - 1 - i) { pp -= FF - 1 - i; ++i; }
        pi[t] = (short)i;
        pj[t] = (short)(i + 1 + pp);
    }
    __syncthreads();

    const int wave = t >> 6;
    const int lane = t & 63;
    const int b = sbase + wave;

    // Per-wave byte-offset tables: offA[p] = &W[j, g_i], offB[p] = &W[i, g_j].
    // Max offset ~512MB fits in u32.
    for (int q = lane; q < 2 * NPP; q += 64) {
        if (q < NPP) {
            const int p = q;
            offA[wave][p] = (unsigned)(pj[p] * TOTAL + g[wave][pi[p]]) * (DD * 4);
        } else {
            const int p = q - NPP;
            offB[wave][p] = (unsigned)(pi[p] * TOTAL + g[wave][pj[p]]) * (DD * 4);
        }
    }
    __syncthreads();

    const int grp = lane >> 4;               // which of 4 pairs this lane serves
    const unsigned chunk = (lane & 15) * 16; // 16B float4 chunk within 256B row
    const char* Wb = (const char*)W;

    float a0 = 0.f, a1 = 0.f, a2 = 0.f, a3 = 0.f;

#pragma unroll 4
    for (int it = 0; it < 47; ++it) {        // 47*4 = 188 pairs
        const int p = it * 4 + grp;
        const float4 va = *(const float4*)(Wb + (offA[wave][p] + chunk));
        const float4 vb = *(const float4*)(Wb + (offB[wave][p] + chunk));
        a0 = fmaf(va.x, vb.x, a0);
        a1 = fmaf(va.y, vb.y, a1);
        a2 = fmaf(va.z, vb.z, a2);
        a3 = fmaf(va.w, vb.w, a3);
    }
    // Pairs 188, 189 on lane groups 0,1.
    if (grp < 2) {
        const int p = 188 + grp;
        const float4 va = *(const float4*)(Wb + (offA[wave][p] + chunk));
        const float4 vb = *(const float4*)(Wb + (offB[wave][p] + chunk));
        a0 = fmaf(va.x, vb.x, a0);
        a1 = fmaf(va.y, vb.y, a1);
        a2 = fmaf(va.z, vb.z, a2);
        a3 = fmaf(va.w, vb.w, a3);
    }
    float acc = (a0 + a1) + (a2 + a3);

    // Linear term: lanes 0..19 each add one Wl entry.
    if (lane < FF) acc += Wl[g[wave][lane]];

    // Wave-64 reduction.
#pragma unroll
    for (int off = 32; off > 0; off >>= 1)
        acc += __shfl_down(acc, off, 64);

    if (lane == 0)
        out[b] = 1.f / (1.f + expf(-(acc + bias[0])));
}

extern "C" void kernel_launch(void* const* d_in, const int* in_sizes, int n_in,
                              void* d_out, int out_size, void* d_ws, size_t ws_size,
                              hipStream_t stream) {
    const int*   x    = (const int*)d_in[0];
    const float* W    = (const float*)d_in[1];
    const float* Wl   = (const float*)d_in[2];
    const float* bias = (const float*)d_in[3];
    float* out = (float*)d_out;

    const int nB = out_size;            // 8192 samples
    dim3 grid(nB / SPB), block(256);
    hipLaunchKernelGGL(ffm_kernel, grid, block, 0, stream,
                       x, W, Wl, bias, out);
}